// Round 10
// baseline (156.047 us; speedup 1.0000x reference)
//
#include <hip/hip_runtime.h>
#include <hip/hip_fp16.h>
#include <cstdint>

#define BB 2
#define SS 512
#define EE 256
#define NN (BB*SS)           // 1024 rows
#define KTOT (EE*EE)         // 65536
#define SPLITK 32
#define KCHUNK (KTOT/SPLITK) // 2048
#define NSTEP (KCHUNK/32)    // 64 k-steps per chunk
#define LN_EPS 1e-3f

typedef _Float16 f16;
typedef _Float16 f16x8 __attribute__((ext_vector_type(8)));
typedef float    f32x4 __attribute__((ext_vector_type(4)));

// ---------------- Kernel 1a: tiled triangular weighted prefix partials.
__global__ void wprefix_kernel(const float* __restrict__ x, float* __restrict__ ps) {
    __shared__ float xt[64][128];
    __shared__ float wl2[576];
    const int id = blockIdx.x;             // 144 blocks
    const int eh = id & 1;
    const int rest = id >> 1;
    const int b = rest / 36;
    const int r = rest % 36;
    int it = 0;
    while ((it + 1) * (it + 2) / 2 <= r) ++it;
    const int jt = r - it * (it + 1) / 2;
    const int tid = threadIdx.x;

    for (int t = tid; t < 576; t += 256) {
        const int d = t - 64;
        wl2[t] = (d > 0) ? 1.0f / ((float)d * (float)d) : 0.0f;
    }
    const int jbase = jt * 64, ibase = it * 64;
    const float* xb = x + ((size_t)b * SS + jbase) * EE + eh * 128;
    #pragma unroll
    for (int p = 0; p < 8; ++p) {
        const int row = p * 8 + (tid >> 5);
        const int col = (tid & 31) * 4;
        *(float4*)&xt[row][col] = *(const float4*)(xb + (size_t)row * EE + col);
    }
    __syncthreads();

    const int g  = tid >> 5;
    const int ec = (tid & 31) * 4;
    const int irow = ibase + g * 8;
    float4 acc[8];
    #pragma unroll
    for (int m = 0; m < 8; ++m) acc[m] = (float4){0.f, 0.f, 0.f, 0.f};

    for (int jj = 0; jj < 64; ++jj) {
        const float4 xv = *(const float4*)&xt[jj][ec];
        const int wbase = irow - (jbase + jj) + 64;
        #pragma unroll
        for (int m = 0; m < 8; ++m) {
            const float w = wl2[wbase + m];
            acc[m].x += xv.x * w;
            acc[m].y += xv.y * w;
            acc[m].z += xv.z * w;
            acc[m].w += xv.w * w;
        }
    }

    float* base = ps + ((size_t)(((b * 2 + eh) * 8 + it) * 8 + jt)) * (64 * 128);
    #pragma unroll
    for (int m = 0; m < 8; ++m)
        *(float4*)(base + (size_t)(g * 8 + m) * 128 + ec) = acc[m];
}

// ---------------- Kernel 1b: fold j-tile partials -> s[n,e]
__global__ void reduce_s_kernel(const float* __restrict__ ps, float* __restrict__ s) {
    const int n = blockIdx.x;
    const int e = threadIdx.x;
    const int b = n >> 9, i = n & (SS - 1);
    const int it = i >> 6, il = i & 63;
    const int eh = e >> 7, ec = e & 127;
    const size_t tbase = (size_t)((b * 2 + eh) * 8 + it) * 8;
    float acc = 0.0f;
    for (int jt = 0; jt <= it; ++jt)
        acc += ps[(tbase + jt) * (64 * 128) + (size_t)il * 128 + ec];
    s[(size_t)n * EE + e] = acc;
}

// ---------------- Kernel 2: split-K MFMA GEMM — barrier-free, reg-staged
// DIRECTLY from f32 cm (no pack kernel, no cmP). Lane l of wave w owns row
// c = w*64+l: per step it loads that row's 128B (8 x dwordx4), converts to
// f16, ds_writes to the same per-wave LDS slice R8 used. Loads issued 2
// steps ahead, LDS write 1 step ahead, counted vmcnt — all in-wave.
__launch_bounds__(256, 2)
__global__ void gemm_kernel(const float* __restrict__ x,
                            const float* __restrict__ sbuf,
                            const float* __restrict__ cm,
                            float* __restrict__ part) {
    __shared__ __align__(16) f16 Bs[4][8192];   // 4 x 16 KB
    const int tid  = threadIdx.x;
    const int lane = tid & 63;
    const int wave = tid >> 6;       // col-quarter 0..3
    const int koct = lane >> 4;      // k-octet 0..3
    const int cl   = lane & 15;

    const int d = blockIdx.x;            // 0..511
    const int nblock = (d >> 3) & 15;
    const int chunk  = (d & 7) * 4 + (d >> 7);   // XCD-grouped chunks

    // ---- A preload: x fragment (8 f16 per rt = 16 VGPRs total).
    f16x8 xf[4];
    #pragma unroll
    for (int rt = 0; rt < 4; ++rt) {
        const int r = nblock * 64 + rt * 16 + cl;
        const float* xr = x + (size_t)r * EE + chunk * 8;
        float4 xlo = *(const float4*)(xr);
        float4 xhi = *(const float4*)(xr + 4);
        xf[rt] = (f16x8){ (f16)xlo.x, (f16)xlo.y, (f16)xlo.z, (f16)xlo.w,
                          (f16)xhi.x, (f16)xhi.y, (f16)xhi.z, (f16)xhi.w };
    }

    f32x4 acc[4][4];
    #pragma unroll
    for (int a = 0; a < 4; ++a)
        #pragma unroll
        for (int b = 0; b < 4; ++b) acc[a][b] = (f32x4){0.f, 0.f, 0.f, 0.f};

    // my staged row: c = wave*64 + lane; source base in cm for this chunk
    const float* myrow = cm + (size_t)(wave * 64 + lane) * KTOT + chunk * KCHUNK;
    // step v covers k-block t = ((v&7)<<3)|(v>>3), i.e. k0 = t*32
    #define K0(v) ((((v & 7) << 3) | (v >> 3)) * 32)

    float4 gv[2][8];   // [step parity][2 float4 per slot x 4 slots]
    #define LOADV(v) do {                                                   \
        const float* src_ = myrow + K0(v);                                  \
        _Pragma("unroll")                                                   \
        for (int i_ = 0; i_ < 4; ++i_) {                                    \
            gv[(v) & 1][i_ * 2 + 0] = *(const float4*)(src_ + i_ * 8);      \
            gv[(v) & 1][i_ * 2 + 1] = *(const float4*)(src_ + i_ * 8 + 4);  \
        }                                                                   \
    } while (0)

    // cvt + ds_write step u's data (held in gv[u&1]) into buf u&3.
    char* const myl = (char*)&Bs[0][0] + wave * 1024 + lane * 16;
    #define WRITEV(u) do {                                                  \
        char* lb_ = myl + ((u) & 3) * 16384;                                \
        _Pragma("unroll")                                                   \
        for (int i_ = 0; i_ < 4; ++i_) {                                    \
            float4 lo_ = gv[(u) & 1][i_ * 2 + 0];                           \
            float4 hi_ = gv[(u) & 1][i_ * 2 + 1];                           \
            f16x8 h_ = { (f16)lo_.x, (f16)lo_.y, (f16)lo_.z, (f16)lo_.w,    \
                         (f16)hi_.x, (f16)hi_.y, (f16)hi_.z, (f16)hi_.w };  \
            *(f16x8*)(lb_ + i_ * 4096) = h_;                                \
        }                                                                   \
    } while (0)

    // B-frag read base (f16 idx): koct slot + wave slice + col-low
    const int cb = koct * 2048 + (wave * 64 + cl) * 8;

    // ---- prologue: svm(m=0) loads + L(0), L(1); write buf0.
    f16x8 svm[4];
    #pragma unroll
    for (int rt = 0; rt < 4; ++rt) {
        const int r = nblock * 64 + rt * 16 + cl;
        const float* sr = sbuf + (size_t)r * EE + koct * 8;
        float4 lo = *(const float4*)(sr);
        float4 hi = *(const float4*)(sr + 4);
        svm[rt] = (f16x8){ (f16)lo.x, (f16)lo.y, (f16)lo.z, (f16)lo.w,
                           (f16)hi.x, (f16)hi.y, (f16)hi.z, (f16)hi.w };
    }
    LOADV(0); LOADV(1);
    asm volatile("s_waitcnt vmcnt(8)" ::: "memory");   // L(0) (+svm) arrived
    WRITEV(0);

    #pragma unroll
    for (int m = 0; m < 8; ++m) {
        if (m > 0) {
            #pragma unroll
            for (int rt = 0; rt < 4; ++rt) {
                const int r = nblock * 64 + rt * 16 + cl;
                const float* sr = sbuf + (size_t)r * EE + m * 32 + koct * 8;
                float4 lo = *(const float4*)(sr);
                float4 hi = *(const float4*)(sr + 4);
                svm[rt] = (f16x8){ (f16)lo.x, (f16)lo.y, (f16)lo.z, (f16)lo.w,
                                   (f16)hi.x, (f16)hi.y, (f16)hi.z, (f16)hi.w };
            }
        }
        #pragma unroll
        for (int a_l = 0; a_l < 8; ++a_l) {
            const int v = m * 8 + a_l;

            // B fragments for this step (4 x ds_read_b128); buf v&3 was
            // written at step v-1 (in-wave DS order + lgkm dependency).
            const f16* bb = &Bs[0][0] + (size_t)(v & 3) * 8192 + cb;
            f16x8 bf[4];
            #pragma unroll
            for (int ct = 0; ct < 4; ++ct)
                bf[ct] = *(const f16x8*)(bb + ct * 128);

            // A fragment for this step
            f16x8 af[4];
            #pragma unroll
            for (int rt = 0; rt < 4; ++rt) {
                const f16 xa = xf[rt][a_l];
                #pragma unroll
                for (int j = 0; j < 8; ++j) af[rt][j] = xa * svm[rt][j];
            }

            // MFMA cluster (16)
            __builtin_amdgcn_s_setprio(1);
            #pragma unroll
            for (int ct = 0; ct < 4; ++ct)
                #pragma unroll
                for (int rt = 0; rt < 4; ++rt)
                    acc[rt][ct] = __builtin_amdgcn_mfma_f32_16x16x32_f16(af[rt], bf[ct], acc[rt][ct], 0, 0, 0);
            __builtin_amdgcn_s_setprio(0);

            // issue loads 2 ahead; complete step v+1's; write buf (v+1).
            if (v <= 61) LOADV(v + 2);
            if (v <= 61)      asm volatile("s_waitcnt vmcnt(8)" ::: "memory");
            else if (v == 62) asm volatile("s_waitcnt vmcnt(0)" ::: "memory");
            if (v <= 62) WRITEV(v + 1);
        }
    }
    #undef K0
    #undef LOADV
    #undef WRITEV

    // Epilogue: C/D layout col = lane&15, row = (lane>>4)*4 + reg ; f32 stores
    #pragma unroll
    for (int rt = 0; rt < 4; ++rt) {
        #pragma unroll
        for (int ct = 0; ct < 4; ++ct) {
            const int c  = wave * 64 + ct * 16 + cl;
            const int rb = nblock * 64 + rt * 16 + koct * 4;
            #pragma unroll
            for (int q = 0; q < 4; ++q)
                part[((size_t)chunk * NN + rb + q) * EE + c] = acc[rt][ct][q];
        }
    }
}

// ---------------- Kernel 3: split-K reduce + residual + LayerNorm
__global__ void reduce_ln_kernel(const float* __restrict__ x,
                                 const float* __restrict__ part,
                                 const float* __restrict__ gamma,
                                 const float* __restrict__ beta,
                                 float* __restrict__ out) {
    const int n = blockIdx.x;
    const int c = threadIdx.x;
    const int lane = c & 63, wave = c >> 6;
    float y = x[(size_t)n * EE + c];
    #pragma unroll 8
    for (int ch = 0; ch < SPLITK; ++ch)
        y += part[((size_t)ch * NN + n) * EE + c];

    float v = y;
    #pragma unroll
    for (int o = 32; o > 0; o >>= 1) v += __shfl_xor(v, o);
    __shared__ float red[8];
    if (lane == 0) red[wave] = v;
    __syncthreads();
    const float mean = (red[0] + red[1] + red[2] + red[3]) * (1.0f / EE);
    const float d = y - mean;
    float sq = d * d;
    #pragma unroll
    for (int o = 32; o > 0; o >>= 1) sq += __shfl_xor(sq, o);
    if (lane == 0) red[4 + wave] = sq;
    __syncthreads();
    const float var = (red[4] + red[5] + red[6] + red[7]) * (1.0f / EE);
    out[(size_t)n * EE + c] = d * rsqrtf(var + LN_EPS) * gamma[c] + beta[c];
}

extern "C" void kernel_launch(void* const* d_in, const int* in_sizes, int n_in,
                              void* d_out, int out_size, void* d_ws, size_t ws_size,
                              hipStream_t stream) {
    const float* x     = (const float*)d_in[0];
    const float* cm    = (const float*)d_in[1];
    const float* gamma = (const float*)d_in[2];
    const float* beta  = (const float*)d_in[3];
    float* out = (float*)d_out;

    float* sbuf = (float*)d_ws;                                    // 1 MB
    float* part = sbuf + (size_t)NN * EE;                          // 33.5 MB
    float* ps   = part;   // prefix partials (8.4 MB) alias part — consumed
                          // by reduce_s before gemm writes part.

    hipLaunchKernelGGL(wprefix_kernel, dim3(144), dim3(256), 0, stream, x, ps);
    hipLaunchKernelGGL(reduce_s_kernel, dim3(NN), dim3(256), 0, stream, ps, sbuf);
    hipLaunchKernelGGL(gemm_kernel, dim3(16 * SPLITK), dim3(256), 0, stream,
                       x, sbuf, cm, part);
    hipLaunchKernelGGL(reduce_ln_kernel, dim3(NN), dim3(256), 0, stream,
                       x, part, gamma, beta, out);
}

// Round 11
// 85.719 us; speedup vs baseline: 1.8204x; 1.8204x over previous
//
#include <hip/hip_runtime.h>
#include <hip/hip_fp16.h>
#include <cstdint>

#define BB 2
#define SS 512
#define EE 256
#define NN (BB*SS)           // 1024 rows
#define KTOT (EE*EE)         // 65536
#define SPLITK 32
#define KCHUNK (KTOT/SPLITK) // 2048
#define NSTEP (KCHUNK/32)    // 64 k-steps per chunk
#define TSTEPS (KTOT/32)     // 2048 total k-steps
#define LN_EPS 1e-3f

typedef _Float16 f16;
typedef _Float16 f16x8 __attribute__((ext_vector_type(8)));
typedef float    f32x4 __attribute__((ext_vector_type(4)));

// ---------------- Kernel 1a: tiled triangular weighted prefix partials.
__global__ void wprefix_kernel(const float* __restrict__ x, float* __restrict__ ps) {
    __shared__ float xt[64][128];
    __shared__ float wl2[576];
    const int id = blockIdx.x;             // 144 blocks
    const int eh = id & 1;
    const int rest = id >> 1;
    const int b = rest / 36;
    const int r = rest % 36;
    int it = 0;
    while ((it + 1) * (it + 2) / 2 <= r) ++it;
    const int jt = r - it * (it + 1) / 2;
    const int tid = threadIdx.x;

    for (int t = tid; t < 576; t += 256) {
        const int d = t - 64;
        wl2[t] = (d > 0) ? 1.0f / ((float)d * (float)d) : 0.0f;
    }
    const int jbase = jt * 64, ibase = it * 64;
    const float* xb = x + ((size_t)b * SS + jbase) * EE + eh * 128;
    #pragma unroll
    for (int p = 0; p < 8; ++p) {
        const int row = p * 8 + (tid >> 5);
        const int col = (tid & 31) * 4;
        *(float4*)&xt[row][col] = *(const float4*)(xb + (size_t)row * EE + col);
    }
    __syncthreads();

    const int g  = tid >> 5;
    const int ec = (tid & 31) * 4;
    const int irow = ibase + g * 8;
    float4 acc[8];
    #pragma unroll
    for (int m = 0; m < 8; ++m) acc[m] = (float4){0.f, 0.f, 0.f, 0.f};

    for (int jj = 0; jj < 64; ++jj) {
        const float4 xv = *(const float4*)&xt[jj][ec];
        const int wbase = irow - (jbase + jj) + 64;
        #pragma unroll
        for (int m = 0; m < 8; ++m) {
            const float w = wl2[wbase + m];
            acc[m].x += xv.x * w;
            acc[m].y += xv.y * w;
            acc[m].z += xv.z * w;
            acc[m].w += xv.w * w;
        }
    }

    float* base = ps + ((size_t)(((b * 2 + eh) * 8 + it) * 8 + jt)) * (64 * 128);
    #pragma unroll
    for (int m = 0; m < 8; ++m)
        *(float4*)(base + (size_t)(g * 8 + m) * 128 + ec) = acc[m];
}

// ---------------- Kernel 1b: fold j-tile partials -> s[n,e]
__global__ void reduce_s_kernel(const float* __restrict__ ps, float* __restrict__ s) {
    const int n = blockIdx.x;
    const int e = threadIdx.x;
    const int b = n >> 9, i = n & (SS - 1);
    const int it = i >> 6, il = i & 63;
    const int eh = e >> 7, ec = e & 127;
    const size_t tbase = (size_t)((b * 2 + eh) * 8 + it) * 8;
    float acc = 0.0f;
    for (int jt = 0; jt <= it; ++jt)
        acc += ps[(tbase + jt) * (64 * 128) + (size_t)il * 128 + ec];
    s[(size_t)n * EE + e] = acc;
}

// ---------------- Kernel 2: pack/transpose cm f32 -> cmP f16 in GEMM staging order.
// Block t covers k in [t*32,+32). Layout: idx = slot*2048 + c*8 + j
//   <-> cm[c][t*32 + slot*8 + j]
__global__ void pack_kernel(const float* __restrict__ cm, f16* __restrict__ cmP) {
    const int t    = blockIdx.x;
    const int tid  = threadIdx.x;
    const int slot = tid >> 6;
    const int cq   = (tid & 63) * 4;
    const float* src = cm + (size_t)t * 32 + slot * 8;
    f16* dst = cmP + (size_t)t * 8192 + tid * 32;
    #pragma unroll
    for (int u = 0; u < 4; ++u) {
        const float* row = src + (size_t)(cq + u) * KTOT;
        float4 lo = *(const float4*)(row);
        float4 hi = *(const float4*)(row + 4);
        f16x8 h = { (f16)lo.x, (f16)lo.y, (f16)lo.z, (f16)lo.w,
                    (f16)hi.x, (f16)hi.y, (f16)hi.z, (f16)hi.w };
        *(f16x8*)(dst + u * 8) = h;
    }
}

// ---------------- Kernel 3: split-K MFMA GEMM — barrier-free (R8) + deep
// in-wave ILP: bf(v+1)/af(v+1) prefetched at the tail of step v, so each
// step starts with only an lgkm wait before its MFMA cluster.
__launch_bounds__(256, 2)
__global__ void gemm_kernel(const float* __restrict__ x,
                            const float* __restrict__ sbuf,
                            const f16* __restrict__ cmP,
                            float* __restrict__ part) {
    __shared__ __align__(16) f16 Bs[4][8192];   // 4 x 16 KB
    const int tid  = threadIdx.x;
    const int lane = tid & 63;
    const int wave = tid >> 6;       // col-quarter 0..3
    const int koct = lane >> 4;      // k-octet 0..3
    const int cl   = lane & 15;

    const int d = blockIdx.x;            // 0..511
    const int nblock = (d >> 3) & 15;
    const int chunk  = (d & 7) * 4 + (d >> 7);   // XCD-grouped chunks

    // ---- xf loads (8 global loads)
    f16x8 xf[4];
    #pragma unroll
    for (int rt = 0; rt < 4; ++rt) {
        const int r = nblock * 64 + rt * 16 + cl;
        const float* xr = x + (size_t)r * EE + chunk * 8;
        float4 xlo = *(const float4*)(xr);
        float4 xhi = *(const float4*)(xr + 4);
        xf[rt] = (f16x8){ (f16)xlo.x, (f16)xlo.y, (f16)xlo.z, (f16)xlo.w,
                          (f16)xhi.x, (f16)xhi.y, (f16)xhi.z, (f16)xhi.w };
    }
    // ---- svm m=0 loads (8 global loads)
    float4 p0[4][2];
    #pragma unroll
    for (int rt = 0; rt < 4; ++rt) {
        const int r = nblock * 64 + rt * 16 + cl;
        const float* sr = sbuf + (size_t)r * EE + koct * 8;
        p0[rt][0] = *(const float4*)(sr);
        p0[rt][1] = *(const float4*)(sr + 4);
    }
    __builtin_amdgcn_sched_barrier(0);   // pin: xf/svm issued before stages

    f32x4 acc[4][4];
    #pragma unroll
    for (int a = 0; a < 4; ++a)
        #pragma unroll
        for (int b = 0; b < 4; ++b) acc[a][b] = (f32x4){0.f, 0.f, 0.f, 0.f};

    const char* srcBase = (const char*)cmP + (size_t)(chunk * NSTEP) * 16384;
    // visit v -> B block t = ((v&7)<<3)|(v>>3). Wave w stages its own
    // read-set: bytes {i*4096 + w*1024 + lane*16} for i=0..3.
    auto stageV = [&](int v) {
        const int t = ((v & 7) << 3) | (v >> 3);
        const char* g = srcBase + (size_t)t * 16384 + wave * 1024 + lane * 16;
        char* l = (char*)&Bs[v & 3][0] + wave * 1024;
        #pragma unroll
        for (int i = 0; i < 4; ++i) {
            __builtin_amdgcn_global_load_lds(
                (const __attribute__((address_space(1))) void*)(g + i * 4096),
                (__attribute__((address_space(3))) void*)(l + i * 4096),
                16, 0, 0);
        }
    };

    stageV(0); stageV(1); stageV(2);     // 12 loads in flight (per wave)
    asm volatile("s_waitcnt vmcnt(8)" ::: "memory");   // xf, svm, stage(0) done
    __builtin_amdgcn_sched_barrier(0);

    // svm f16
    f16x8 svm[4];
    #pragma unroll
    for (int rt = 0; rt < 4; ++rt)
        svm[rt] = (f16x8){ (f16)p0[rt][0].x, (f16)p0[rt][0].y,
                           (f16)p0[rt][0].z, (f16)p0[rt][0].w,
                           (f16)p0[rt][1].x, (f16)p0[rt][1].y,
                           (f16)p0[rt][1].z, (f16)p0[rt][1].w };

    const int cb = koct * 2048 + (wave * 64 + cl) * 8;

    // bf(0) read + af(0) build
    f16x8 bfc[4], afc[4];
    {
        const f16* bb = &Bs[0][cb];
        #pragma unroll
        for (int ct = 0; ct < 4; ++ct) bfc[ct] = *(const f16x8*)(bb + ct * 128);
        #pragma unroll
        for (int rt = 0; rt < 4; ++rt) {
            const f16 xa = xf[rt][0];
            #pragma unroll
            for (int j = 0; j < 8; ++j) afc[rt][j] = xa * svm[rt][j];
        }
    }

    #pragma unroll
    for (int m = 0; m < 8; ++m) {
        float4 pnxt[4][2];
        #pragma unroll
        for (int a_l = 0; a_l < 8; ++a_l) {
            const int v = m * 8 + a_l;

            // issue next-m svm loads early (order-pinned before MFMA/stage)
            if (a_l == 6 && m < 7) {
                #pragma unroll
                for (int rt = 0; rt < 4; ++rt) {
                    const int r = nblock * 64 + rt * 16 + cl;
                    const float* sr = sbuf + (size_t)r * EE + (m + 1) * 32 + koct * 8;
                    pnxt[rt][0] = *(const float4*)(sr);
                    pnxt[rt][1] = *(const float4*)(sr + 4);
                }
                __builtin_amdgcn_sched_barrier(0);
            }

            // MFMA cluster (16) — operands prefetched last step
            __builtin_amdgcn_s_setprio(1);
            #pragma unroll
            for (int ct = 0; ct < 4; ++ct)
                #pragma unroll
                for (int rt = 0; rt < 4; ++rt)
                    acc[rt][ct] = __builtin_amdgcn_mfma_f32_16x16x32_f16(afc[rt], bfc[ct], acc[rt][ct], 0, 0, 0);
            __builtin_amdgcn_s_setprio(0);

            if (v + 3 < NSTEP) stageV(v + 3);

            // counted waits: guarantee stage(v+1) (and svm at a_l==7) arrived
            if (v <= 60) {
                if (a_l == 6 && m < 7) asm volatile("s_waitcnt vmcnt(16)" ::: "memory");
                else                   asm volatile("s_waitcnt vmcnt(8)"  ::: "memory");
            } else if (v == 61)        asm volatile("s_waitcnt vmcnt(4)"  ::: "memory");
            else if (v == 62)          asm volatile("s_waitcnt vmcnt(0)"  ::: "memory");
            __builtin_amdgcn_sched_barrier(0);

            // tail prefetch: bf(v+1) + af(v+1)
            if (v < 63) {
                const f16* bb = &Bs[0][0] + (size_t)((v + 1) & 3) * 8192 + cb;
                f16x8 bfn[4];
                #pragma unroll
                for (int ct = 0; ct < 4; ++ct) bfn[ct] = *(const f16x8*)(bb + ct * 128);
                if (a_l == 7) {   // new m's svm (loads guaranteed done)
                    #pragma unroll
                    for (int rt = 0; rt < 4; ++rt)
                        svm[rt] = (f16x8){ (f16)pnxt[rt][0].x, (f16)pnxt[rt][0].y,
                                           (f16)pnxt[rt][0].z, (f16)pnxt[rt][0].w,
                                           (f16)pnxt[rt][1].x, (f16)pnxt[rt][1].y,
                                           (f16)pnxt[rt][1].z, (f16)pnxt[rt][1].w };
                }
                f16x8 afn[4];
                #pragma unroll
                for (int rt = 0; rt < 4; ++rt) {
                    const f16 xa = xf[rt][(a_l + 1) & 7];
                    #pragma unroll
                    for (int j = 0; j < 8; ++j) afn[rt][j] = xa * svm[rt][j];
                }
                #pragma unroll
                for (int ct = 0; ct < 4; ++ct) bfc[ct] = bfn[ct];
                #pragma unroll
                for (int rt = 0; rt < 4; ++rt) afc[rt] = afn[rt];
                __builtin_amdgcn_sched_barrier(0);   // keep prefetch in step v
            }
        }
    }

    // Epilogue: C/D layout col = lane&15, row = (lane>>4)*4 + reg ; f32 stores
    #pragma unroll
    for (int rt = 0; rt < 4; ++rt) {
        #pragma unroll
        for (int ct = 0; ct < 4; ++ct) {
            const int c  = wave * 64 + ct * 16 + cl;
            const int rb = nblock * 64 + rt * 16 + koct * 4;
            #pragma unroll
            for (int q = 0; q < 4; ++q)
                part[((size_t)chunk * NN + rb + q) * EE + c] = acc[rt][ct][q];
        }
    }
}

// ---------------- Kernel 4: split-K reduce + residual + LayerNorm
__global__ void reduce_ln_kernel(const float* __restrict__ x,
                                 const float* __restrict__ part,
                                 const float* __restrict__ gamma,
                                 const float* __restrict__ beta,
                                 float* __restrict__ out) {
    const int n = blockIdx.x;
    const int c = threadIdx.x;
    const int lane = c & 63, wave = c >> 6;
    float y = x[(size_t)n * EE + c];
    #pragma unroll 8
    for (int ch = 0; ch < SPLITK; ++ch)
        y += part[((size_t)ch * NN + n) * EE + c];

    float v = y;
    #pragma unroll
    for (int o = 32; o > 0; o >>= 1) v += __shfl_xor(v, o);
    __shared__ float red[8];
    if (lane == 0) red[wave] = v;
    __syncthreads();
    const float mean = (red[0] + red[1] + red[2] + red[3]) * (1.0f / EE);
    const float d = y - mean;
    float sq = d * d;
    #pragma unroll
    for (int o = 32; o > 0; o >>= 1) sq += __shfl_xor(sq, o);
    if (lane == 0) red[4 + wave] = sq;
    __syncthreads();
    const float var = (red[4] + red[5] + red[6] + red[7]) * (1.0f / EE);
    out[(size_t)n * EE + c] = d * rsqrtf(var + LN_EPS) * gamma[c] + beta[c];
}

extern "C" void kernel_launch(void* const* d_in, const int* in_sizes, int n_in,
                              void* d_out, int out_size, void* d_ws, size_t ws_size,
                              hipStream_t stream) {
    const float* x     = (const float*)d_in[0];
    const float* cm    = (const float*)d_in[1];
    const float* gamma = (const float*)d_in[2];
    const float* beta  = (const float*)d_in[3];
    float* out = (float*)d_out;

    float* sbuf = (float*)d_ws;                                    // 1 MB
    f16*   cmP  = (f16*)(sbuf + (size_t)NN * EE);                  // 33.5 MB
    float* part = (float*)((char*)cmP + (size_t)TSTEPS * 8192 * sizeof(f16)); // 33.5 MB
    float* ps   = part;   // prefix partials (8.4 MB) alias part — consumed
                          // by reduce_s before gemm writes part.

    hipLaunchKernelGGL(wprefix_kernel, dim3(144), dim3(256), 0, stream, x, ps);
    hipLaunchKernelGGL(reduce_s_kernel, dim3(NN), dim3(256), 0, stream, ps, sbuf);
    hipLaunchKernelGGL(pack_kernel, dim3(TSTEPS), dim3(256), 0, stream, cm, cmP);
    hipLaunchKernelGGL(gemm_kernel, dim3(16 * SPLITK), dim3(256), 0, stream,
                       x, sbuf, cmP, part);
    hipLaunchKernelGGL(reduce_ln_kernel, dim3(NN), dim3(256), 0, stream,
                       x, part, gamma, beta, out);
}